// Round 1
// baseline (592.748 us; speedup 1.0000x reference)
//
#include <hip/hip_runtime.h>

#define N_NODES 50000
#define N_EDGES 600000
#define D 128

// ---------------- Stage 1: per-edge gather + atomic scatter-sum ----------------
// One wave (64 lanes) per edge; lane l covers columns 2l, 2l+1 (float2).
// unsafeAtomicAdd -> global_atomic_add_f32 (no CAS loop) on gfx950.
__global__ __launch_bounds__(256) void edge_scatter(
    const float* __restrict__ feat, const float* __restrict__ norm,
    const int* __restrict__ src, const int* __restrict__ dst,
    float* __restrict__ accum, int* __restrict__ indeg, int E)
{
    int gid  = blockIdx.x * blockDim.x + threadIdx.x;
    int wid  = gid >> 6;
    int lane = threadIdx.x & 63;
    int nw   = (gridDim.x * blockDim.x) >> 6;
    for (int e = wid; e < E; e += nw) {
        int s = src[e];
        int d = dst[e];
        float nr = norm[s];
        const float2 v = *reinterpret_cast<const float2*>(feat + (size_t)s * D + lane * 2);
        float* a = accum + (size_t)d * D + lane * 2;
        unsafeAtomicAdd(a,     v.x * nr);
        unsafeAtomicAdd(a + 1, v.y * nr);
        if (lane == 0) atomicAdd(indeg + d, 1);
    }
}

// ---------------- Stage 2: h = mask ? accum*norm : feature; out = relu(h@W^T + b) ----------------
// Block = 256 threads handles 8 node rows. W staged in LDS with 132-float padded
// stride (row start bank = 4j mod 32 -> spreads banks); h rows staged unpadded
// (reads are broadcast within 32-thread row groups).
__global__ __launch_bounds__(256) void node_apply(
    const float* __restrict__ feat, const float* __restrict__ norm,
    const float* __restrict__ W, const float* __restrict__ bias,
    const float* __restrict__ accum, const int* __restrict__ indeg,
    float* __restrict__ out)
{
    __shared__ __align__(16) float wsh[128 * 132];
    __shared__ __align__(16) float hsh[8 * 128];
    const int t = threadIdx.x;

    // stage W: 16384 floats = 4096 float4, 16 per thread
    #pragma unroll
    for (int i = 0; i < 16; ++i) {
        int p = t + 256 * i;          // float4 index
        int j = p >> 5;               // row of W
        int k = (p & 31) * 4;         // col of W
        float4 w = *reinterpret_cast<const float4*>(W + (size_t)p * 4);
        *reinterpret_cast<float4*>(&wsh[j * 132 + k]) = w;
    }

    // stage h: thread t loads one float4 of row n0 = t>>5
    {
        int n0 = t >> 5;
        int kk = (t & 31) * 4;
        int g  = blockIdx.x * 8 + n0;   // 50000 = 6250*8, always in range
        float4 hv;
        if (indeg[g] > 0) {
            float4 a = *reinterpret_cast<const float4*>(accum + (size_t)g * D + kk);
            float nr = norm[g];
            hv = make_float4(a.x * nr, a.y * nr, a.z * nr, a.w * nr);
        } else {
            hv = *reinterpret_cast<const float4*>(feat + (size_t)g * D + kk);
        }
        *reinterpret_cast<float4*>(&hsh[n0 * 128 + kk]) = hv;
    }
    __syncthreads();

    const int r = t >> 5;       // row within block (0..7)
    const int q = t & 31;       // base output column
    float acc0 = 0.f, acc1 = 0.f, acc2 = 0.f, acc3 = 0.f;
    #pragma unroll
    for (int k = 0; k < 128; k += 4) {
        float4 hv = *reinterpret_cast<const float4*>(&hsh[r * 128 + k]);
        float4 w0 = *reinterpret_cast<const float4*>(&wsh[(q     ) * 132 + k]);
        float4 w1 = *reinterpret_cast<const float4*>(&wsh[(q + 32) * 132 + k]);
        float4 w2 = *reinterpret_cast<const float4*>(&wsh[(q + 64) * 132 + k]);
        float4 w3 = *reinterpret_cast<const float4*>(&wsh[(q + 96) * 132 + k]);
        acc0 += hv.x * w0.x + hv.y * w0.y + hv.z * w0.z + hv.w * w0.w;
        acc1 += hv.x * w1.x + hv.y * w1.y + hv.z * w1.z + hv.w * w1.w;
        acc2 += hv.x * w2.x + hv.y * w2.y + hv.z * w2.z + hv.w * w2.w;
        acc3 += hv.x * w3.x + hv.y * w3.y + hv.z * w3.z + hv.w * w3.w;
    }

    const size_t ob = (size_t)(blockIdx.x * 8 + r) * D;
    float r0 = acc0 + bias[q];
    float r1 = acc1 + bias[q + 32];
    float r2 = acc2 + bias[q + 64];
    float r3 = acc3 + bias[q + 96];
    out[ob + q]      = r0 > 0.f ? r0 : 0.f;
    out[ob + q + 32] = r1 > 0.f ? r1 : 0.f;
    out[ob + q + 64] = r2 > 0.f ? r2 : 0.f;
    out[ob + q + 96] = r3 > 0.f ? r3 : 0.f;
}

extern "C" void kernel_launch(void* const* d_in, const int* in_sizes, int n_in,
                              void* d_out, int out_size, void* d_ws, size_t ws_size,
                              hipStream_t stream) {
    const float* feat = (const float*)d_in[0];   // [50000,128]
    const float* norm = (const float*)d_in[1];   // [50000,1]
    const float* W    = (const float*)d_in[2];   // [128,128]
    const float* bias = (const float*)d_in[3];   // [128]
    const int*   src  = (const int*)d_in[4];     // [600000]
    const int*   dst  = (const int*)d_in[5];     // [600000]
    float* out = (float*)d_out;

    float* accum = (float*)d_ws;
    int*   indeg = (int*)((char*)d_ws + (size_t)N_NODES * D * sizeof(float));

    size_t zero_bytes = (size_t)N_NODES * D * sizeof(float) + (size_t)N_NODES * sizeof(int);
    hipMemsetAsync(d_ws, 0, zero_bytes, stream);

    edge_scatter<<<2048, 256, 0, stream>>>(feat, norm, src, dst, accum, indeg, N_EDGES);
    node_apply<<<N_NODES / 8, 256, 0, stream>>>(feat, norm, W, bias, accum, indeg, out);
}

// Round 2
// 288.370 us; speedup vs baseline: 2.0555x; 2.0555x over previous
//
#include <hip/hip_runtime.h>

#define N_NODES 50000
#define N_EDGES 600000
#define D 128

// ---------------- CSR build: histogram ----------------
__global__ __launch_bounds__(256) void hist_kernel(
    const int* __restrict__ dst, int* __restrict__ counts, int E)
{
    int e = blockIdx.x * blockDim.x + threadIdx.x;
    if (e < E) atomicAdd(&counts[dst[e]], 1);
}

// ---------------- CSR build: exclusive scan over 50000 counts ----------------
__global__ __launch_bounds__(1024) void scan_kernel(
    const int* __restrict__ counts, int* __restrict__ offsets, int* __restrict__ cursor)
{
    __shared__ int sums[1024];
    const int t = threadIdx.x;
    const int CH = (N_NODES + 1023) / 1024;   // 49
    const int base = t * CH;
    const int lim = min(base + CH, N_NODES);

    int s = 0;
    for (int i = base; i < lim; ++i) s += counts[i];
    sums[t] = s;
    __syncthreads();
    for (int off = 1; off < 1024; off <<= 1) {
        int v = (t >= off) ? sums[t - off] : 0;
        __syncthreads();
        sums[t] += v;
        __syncthreads();
    }
    int run = sums[t] - s;   // exclusive prefix
    for (int i = base; i < lim; ++i) {
        offsets[i] = run;
        cursor[i]  = run;
        run += counts[i];
    }
}

// ---------------- CSR build: scatter edge srcs into buckets ----------------
__global__ __launch_bounds__(256) void fill_kernel(
    const int* __restrict__ src, const int* __restrict__ dst,
    int* __restrict__ cursor, int* __restrict__ csr_src, int E)
{
    int e = blockIdx.x * blockDim.x + threadIdx.x;
    if (e < E) {
        int d = dst[e];
        int slot = atomicAdd(&cursor[d], 1);
        csr_src[slot] = src[e];
    }
}

// ---------------- Gather-reduce: one wave per node, no float atomics ----------------
// lane l accumulates columns 2l, 2l+1 in registers.
__global__ __launch_bounds__(256) void gather_kernel(
    const float* __restrict__ feat, const float* __restrict__ norm,
    const int* __restrict__ offsets, const int* __restrict__ counts,
    const int* __restrict__ csr_src, float* __restrict__ h)
{
    int wid  = (blockIdx.x * blockDim.x + threadIdx.x) >> 6;
    int lane = threadIdx.x & 63;
    if (wid >= N_NODES) return;

    const size_t hb = (size_t)wid * D + lane * 2;
    const int deg = counts[wid];
    if (deg == 0) {
        // zero in-degree: keep original feature
        float2 v = *reinterpret_cast<const float2*>(feat + hb);
        *reinterpret_cast<float2*>(h + hb) = v;
        return;
    }

    const int base = offsets[wid];
    float a0 = 0.f, a1 = 0.f;
    int i = 0;
    for (; i + 2 <= deg; i += 2) {
        int s0 = csr_src[base + i];
        int s1 = csr_src[base + i + 1];
        float n0 = norm[s0];
        float n1 = norm[s1];
        float2 v0 = *reinterpret_cast<const float2*>(feat + (size_t)s0 * D + lane * 2);
        float2 v1 = *reinterpret_cast<const float2*>(feat + (size_t)s1 * D + lane * 2);
        a0 += v0.x * n0 + v1.x * n1;
        a1 += v0.y * n0 + v1.y * n1;
    }
    if (i < deg) {
        int s0 = csr_src[base + i];
        float n0 = norm[s0];
        float2 v0 = *reinterpret_cast<const float2*>(feat + (size_t)s0 * D + lane * 2);
        a0 += v0.x * n0;
        a1 += v0.y * n0;
    }
    float nd = norm[wid];
    float2 hv = make_float2(a0 * nd, a1 * nd);
    *reinterpret_cast<float2*>(h + hb) = hv;
}

// ---------------- Node apply: out = relu(h @ W^T + b) ----------------
__global__ __launch_bounds__(256) void node_apply(
    const float* __restrict__ h, const float* __restrict__ W,
    const float* __restrict__ bias, float* __restrict__ out)
{
    __shared__ __align__(16) float wsh[128 * 132];
    __shared__ __align__(16) float hsh[8 * 128];
    const int t = threadIdx.x;

    // stage W: 16384 floats = 4096 float4, 16 per thread
    #pragma unroll
    for (int i = 0; i < 16; ++i) {
        int p = t + 256 * i;          // float4 index
        int j = p >> 5;               // row of W
        int k = (p & 31) * 4;         // col of W
        float4 w = *reinterpret_cast<const float4*>(W + (size_t)p * 4);
        *reinterpret_cast<float4*>(&wsh[j * 132 + k]) = w;
    }

    // stage h rows: thread t loads one float4 of row n0 = t>>5
    {
        int n0 = t >> 5;
        int kk = (t & 31) * 4;
        int g  = blockIdx.x * 8 + n0;   // 50000 = 6250*8, always in range
        float4 hv = *reinterpret_cast<const float4*>(h + (size_t)g * D + kk);
        *reinterpret_cast<float4*>(&hsh[n0 * 128 + kk]) = hv;
    }
    __syncthreads();

    const int r = t >> 5;       // row within block (0..7)
    const int q = t & 31;       // base output column
    float acc0 = 0.f, acc1 = 0.f, acc2 = 0.f, acc3 = 0.f;
    #pragma unroll
    for (int k = 0; k < 128; k += 4) {
        float4 hv = *reinterpret_cast<const float4*>(&hsh[r * 128 + k]);
        float4 w0 = *reinterpret_cast<const float4*>(&wsh[(q     ) * 132 + k]);
        float4 w1 = *reinterpret_cast<const float4*>(&wsh[(q + 32) * 132 + k]);
        float4 w2 = *reinterpret_cast<const float4*>(&wsh[(q + 64) * 132 + k]);
        float4 w3 = *reinterpret_cast<const float4*>(&wsh[(q + 96) * 132 + k]);
        acc0 += hv.x * w0.x + hv.y * w0.y + hv.z * w0.z + hv.w * w0.w;
        acc1 += hv.x * w1.x + hv.y * w1.y + hv.z * w1.z + hv.w * w1.w;
        acc2 += hv.x * w2.x + hv.y * w2.y + hv.z * w2.z + hv.w * w2.w;
        acc3 += hv.x * w3.x + hv.y * w3.y + hv.z * w3.z + hv.w * w3.w;
    }

    const size_t ob = (size_t)(blockIdx.x * 8 + r) * D;
    float r0 = acc0 + bias[q];
    float r1 = acc1 + bias[q + 32];
    float r2 = acc2 + bias[q + 64];
    float r3 = acc3 + bias[q + 96];
    out[ob + q]      = r0 > 0.f ? r0 : 0.f;
    out[ob + q + 32] = r1 > 0.f ? r1 : 0.f;
    out[ob + q + 64] = r2 > 0.f ? r2 : 0.f;
    out[ob + q + 96] = r3 > 0.f ? r3 : 0.f;
}

extern "C" void kernel_launch(void* const* d_in, const int* in_sizes, int n_in,
                              void* d_out, int out_size, void* d_ws, size_t ws_size,
                              hipStream_t stream) {
    const float* feat = (const float*)d_in[0];   // [50000,128]
    const float* norm = (const float*)d_in[1];   // [50000,1]
    const float* W    = (const float*)d_in[2];   // [128,128]
    const float* bias = (const float*)d_in[3];   // [128]
    const int*   src  = (const int*)d_in[4];     // [600000]
    const int*   dst  = (const int*)d_in[5];     // [600000]
    float* out = (float*)d_out;

    // workspace layout
    char* ws = (char*)d_ws;
    float* h       = (float*)ws;                                   // 25.6 MB
    int*   counts  = (int*)(ws + (size_t)N_NODES * D * sizeof(float));
    int*   offsets = counts + N_NODES;
    int*   cursor  = offsets + N_NODES;
    int*   csr_src = cursor + N_NODES;                             // 2.4 MB

    // zero only the counts array (200 KB)
    hipMemsetAsync(counts, 0, (size_t)N_NODES * sizeof(int), stream);

    const int egrid = (N_EDGES + 255) / 256;
    hist_kernel<<<egrid, 256, 0, stream>>>(dst, counts, N_EDGES);
    scan_kernel<<<1, 1024, 0, stream>>>(counts, offsets, cursor);
    fill_kernel<<<egrid, 256, 0, stream>>>(src, dst, cursor, csr_src, N_EDGES);
    gather_kernel<<<(N_NODES + 3) / 4, 256, 0, stream>>>(feat, norm, offsets, counts, csr_src, h);
    node_apply<<<N_NODES / 8, 256, 0, stream>>>(h, W, bias, out);
}

// Round 3
// 188.915 us; speedup vs baseline: 3.1376x; 1.5264x over previous
//
#include <hip/hip_runtime.h>

#define N_NODES 50000
#define N_EDGES 600000
#define D 128
#define SCAN_NB 49   // ceil(50000 / 1024)

// ---------------- CSR build: histogram ----------------
__global__ __launch_bounds__(256) void hist_kernel(
    const int* __restrict__ dst, int* __restrict__ counts, int E)
{
    int e = blockIdx.x * blockDim.x + threadIdx.x;
    if (e < E) atomicAdd(&counts[dst[e]], 1);
}

// ---------------- Scan stage A: per-block sums (1024 counts/block) ----------------
__global__ __launch_bounds__(256) void scan_partial(
    const int* __restrict__ counts, int* __restrict__ blockSums)
{
    __shared__ int red[256];
    int t = threadIdx.x;
    int idx = (blockIdx.x * 256 + t) * 4;
    int s = 0;
    if (idx < N_NODES) {   // 50000 % 4 == 0: quad never straddles the end
        int4 v = *reinterpret_cast<const int4*>(counts + idx);
        s = v.x + v.y + v.z + v.w;
    }
    red[t] = s;
    __syncthreads();
    for (int off = 128; off > 0; off >>= 1) {
        if (t < off) red[t] += red[t + off];
        __syncthreads();
    }
    if (t == 0) blockSums[blockIdx.x] = red[0];
}

// ---------------- Scan stage B: exclusive prefix over 49 block sums ----------------
__global__ __launch_bounds__(64) void scan_blocksums(int* __restrict__ blockSums)
{
    __shared__ int s[64];
    int t = threadIdx.x;
    s[t] = (t < SCAN_NB) ? blockSums[t] : 0;
    __syncthreads();
    if (t == 0) {
        int run = 0;
        for (int i = 0; i < SCAN_NB; ++i) { int v = s[i]; s[i] = run; run += v; }
    }
    __syncthreads();
    if (t < SCAN_NB) blockSums[t] = s[t];
}

// ---------------- Scan stage C: full exclusive scan, write offsets + cursor ----------------
__global__ __launch_bounds__(256) void scan_final(
    const int* __restrict__ counts, const int* __restrict__ blockPrefix,
    int* __restrict__ offsets, int* __restrict__ cursor)
{
    __shared__ int sums[256];
    int t = threadIdx.x;
    int idx = (blockIdx.x * 256 + t) * 4;
    int4 v = make_int4(0, 0, 0, 0);
    if (idx < N_NODES) v = *reinterpret_cast<const int4*>(counts + idx);
    int s = v.x + v.y + v.z + v.w;
    sums[t] = s;
    __syncthreads();
    for (int off = 1; off < 256; off <<= 1) {
        int u = (t >= off) ? sums[t - off] : 0;
        __syncthreads();
        sums[t] += u;
        __syncthreads();
    }
    int run = blockPrefix[blockIdx.x] + sums[t] - s;   // exclusive prefix for idx
    if (idx < N_NODES) {
        int4 o;
        o.x = run;
        o.y = run + v.x;
        o.z = run + v.x + v.y;
        o.w = run + v.x + v.y + v.z;
        *reinterpret_cast<int4*>(offsets + idx) = o;
        *reinterpret_cast<int4*>(cursor + idx)  = o;
    }
}

// ---------------- CSR build: scatter edge srcs into buckets ----------------
__global__ __launch_bounds__(256) void fill_kernel(
    const int* __restrict__ src, const int* __restrict__ dst,
    int* __restrict__ cursor, int* __restrict__ csr_src, int E)
{
    int e = blockIdx.x * blockDim.x + threadIdx.x;
    if (e < E) {
        int d = dst[e];
        int slot = atomicAdd(&cursor[d], 1);
        csr_src[slot] = src[e];
    }
}

// ---------------- Gather-reduce: one wave per node, no float atomics ----------------
__global__ __launch_bounds__(256) void gather_kernel(
    const float* __restrict__ feat, const float* __restrict__ norm,
    const int* __restrict__ offsets, const int* __restrict__ counts,
    const int* __restrict__ csr_src, float* __restrict__ h)
{
    int wid  = (blockIdx.x * blockDim.x + threadIdx.x) >> 6;
    int lane = threadIdx.x & 63;
    if (wid >= N_NODES) return;

    const size_t hb = (size_t)wid * D + lane * 2;
    const int deg = counts[wid];
    if (deg == 0) {
        float2 v = *reinterpret_cast<const float2*>(feat + hb);
        *reinterpret_cast<float2*>(h + hb) = v;
        return;
    }

    const int base = offsets[wid];
    float a0 = 0.f, a1 = 0.f;
    int i = 0;
    for (; i + 2 <= deg; i += 2) {
        int s0 = csr_src[base + i];
        int s1 = csr_src[base + i + 1];
        float n0 = norm[s0];
        float n1 = norm[s1];
        float2 v0 = *reinterpret_cast<const float2*>(feat + (size_t)s0 * D + lane * 2);
        float2 v1 = *reinterpret_cast<const float2*>(feat + (size_t)s1 * D + lane * 2);
        a0 += v0.x * n0 + v1.x * n1;
        a1 += v0.y * n0 + v1.y * n1;
    }
    if (i < deg) {
        int s0 = csr_src[base + i];
        float n0 = norm[s0];
        float2 v0 = *reinterpret_cast<const float2*>(feat + (size_t)s0 * D + lane * 2);
        a0 += v0.x * n0;
        a1 += v0.y * n0;
    }
    float nd = norm[wid];
    float2 hv = make_float2(a0 * nd, a1 * nd);
    *reinterpret_cast<float2*>(h + hb) = hv;
}

// ---------------- Node apply: out = relu(h @ W^T + b) ----------------
__global__ __launch_bounds__(256) void node_apply(
    const float* __restrict__ h, const float* __restrict__ W,
    const float* __restrict__ bias, float* __restrict__ out)
{
    __shared__ __align__(16) float wsh[128 * 132];
    __shared__ __align__(16) float hsh[8 * 128];
    const int t = threadIdx.x;

    #pragma unroll
    for (int i = 0; i < 16; ++i) {
        int p = t + 256 * i;
        int j = p >> 5;
        int k = (p & 31) * 4;
        float4 w = *reinterpret_cast<const float4*>(W + (size_t)p * 4);
        *reinterpret_cast<float4*>(&wsh[j * 132 + k]) = w;
    }
    {
        int n0 = t >> 5;
        int kk = (t & 31) * 4;
        int g  = blockIdx.x * 8 + n0;
        float4 hv = *reinterpret_cast<const float4*>(h + (size_t)g * D + kk);
        *reinterpret_cast<float4*>(&hsh[n0 * 128 + kk]) = hv;
    }
    __syncthreads();

    const int r = t >> 5;
    const int q = t & 31;
    float acc0 = 0.f, acc1 = 0.f, acc2 = 0.f, acc3 = 0.f;
    #pragma unroll
    for (int k = 0; k < 128; k += 4) {
        float4 hv = *reinterpret_cast<const float4*>(&hsh[r * 128 + k]);
        float4 w0 = *reinterpret_cast<const float4*>(&wsh[(q     ) * 132 + k]);
        float4 w1 = *reinterpret_cast<const float4*>(&wsh[(q + 32) * 132 + k]);
        float4 w2 = *reinterpret_cast<const float4*>(&wsh[(q + 64) * 132 + k]);
        float4 w3 = *reinterpret_cast<const float4*>(&wsh[(q + 96) * 132 + k]);
        acc0 += hv.x * w0.x + hv.y * w0.y + hv.z * w0.z + hv.w * w0.w;
        acc1 += hv.x * w1.x + hv.y * w1.y + hv.z * w1.z + hv.w * w1.w;
        acc2 += hv.x * w2.x + hv.y * w2.y + hv.z * w2.z + hv.w * w2.w;
        acc3 += hv.x * w3.x + hv.y * w3.y + hv.z * w3.z + hv.w * w3.w;
    }

    const size_t ob = (size_t)(blockIdx.x * 8 + r) * D;
    float r0 = acc0 + bias[q];
    float r1 = acc1 + bias[q + 32];
    float r2 = acc2 + bias[q + 64];
    float r3 = acc3 + bias[q + 96];
    out[ob + q]      = r0 > 0.f ? r0 : 0.f;
    out[ob + q + 32] = r1 > 0.f ? r1 : 0.f;
    out[ob + q + 64] = r2 > 0.f ? r2 : 0.f;
    out[ob + q + 96] = r3 > 0.f ? r3 : 0.f;
}

extern "C" void kernel_launch(void* const* d_in, const int* in_sizes, int n_in,
                              void* d_out, int out_size, void* d_ws, size_t ws_size,
                              hipStream_t stream) {
    const float* feat = (const float*)d_in[0];
    const float* norm = (const float*)d_in[1];
    const float* W    = (const float*)d_in[2];
    const float* bias = (const float*)d_in[3];
    const int*   src  = (const int*)d_in[4];
    const int*   dst  = (const int*)d_in[5];
    float* out = (float*)d_out;

    char* ws = (char*)d_ws;
    float* h        = (float*)ws;                                   // 25.6 MB
    int*   counts   = (int*)(ws + (size_t)N_NODES * D * sizeof(float));
    int*   offsets  = counts + N_NODES;
    int*   cursor   = offsets + N_NODES;
    int*   csr_src  = cursor + N_NODES;                             // 2.4 MB
    int*   blockSums = csr_src + N_EDGES;                           // 49 ints

    hipMemsetAsync(counts, 0, (size_t)N_NODES * sizeof(int), stream);

    const int egrid = (N_EDGES + 255) / 256;
    hist_kernel<<<egrid, 256, 0, stream>>>(dst, counts, N_EDGES);
    scan_partial<<<SCAN_NB, 256, 0, stream>>>(counts, blockSums);
    scan_blocksums<<<1, 64, 0, stream>>>(blockSums);
    scan_final<<<SCAN_NB, 256, 0, stream>>>(counts, blockSums, offsets, cursor);
    fill_kernel<<<egrid, 256, 0, stream>>>(src, dst, cursor, csr_src, N_EDGES);
    gather_kernel<<<(N_NODES + 3) / 4, 256, 0, stream>>>(feat, norm, offsets, counts, csr_src, h);
    node_apply<<<N_NODES / 8, 256, 0, stream>>>(h, W, bias, out);
}

// Round 4
// 147.945 us; speedup vs baseline: 4.0065x; 1.2769x over previous
//
#include <hip/hip_runtime.h>

#define N_NODES 50000
#define N_EDGES 600000
#define D 128
#define SCAN_NB 49   // ceil(50000 / 1024)

typedef __attribute__((ext_vector_type(8))) short bf16x8;
typedef __attribute__((ext_vector_type(4))) float f32x4;

__device__ inline unsigned short f2bf(float f) {
    unsigned int u = __builtin_bit_cast(unsigned int, f);
    unsigned int r = (u + 0x7FFFu + ((u >> 16) & 1u)) >> 16;   // RNE
    return (unsigned short)r;
}

// ---------------- CSR build: histogram ----------------
__global__ __launch_bounds__(256) void hist_kernel(
    const int* __restrict__ dst, int* __restrict__ counts, int E)
{
    int e = blockIdx.x * blockDim.x + threadIdx.x;
    if (e < E) atomicAdd(&counts[dst[e]], 1);
}

// ---------------- Scan stage A: per-block sums (1024 counts/block) ----------------
__global__ __launch_bounds__(256) void scan_partial(
    const int* __restrict__ counts, int* __restrict__ blockSums)
{
    __shared__ int red[256];
    int t = threadIdx.x;
    int idx = (blockIdx.x * 256 + t) * 4;
    int s = 0;
    if (idx < N_NODES) {
        int4 v = *reinterpret_cast<const int4*>(counts + idx);
        s = v.x + v.y + v.z + v.w;
    }
    red[t] = s;
    __syncthreads();
    for (int off = 128; off > 0; off >>= 1) {
        if (t < off) red[t] += red[t + off];
        __syncthreads();
    }
    if (t == 0) blockSums[blockIdx.x] = red[0];
}

// ---------------- Scan stage B: exclusive prefix over 49 block sums ----------------
__global__ __launch_bounds__(64) void scan_blocksums(int* __restrict__ blockSums)
{
    __shared__ int s[64];
    int t = threadIdx.x;
    s[t] = (t < SCAN_NB) ? blockSums[t] : 0;
    __syncthreads();
    if (t == 0) {
        int run = 0;
        for (int i = 0; i < SCAN_NB; ++i) { int v = s[i]; s[i] = run; run += v; }
    }
    __syncthreads();
    if (t < SCAN_NB) blockSums[t] = s[t];
}

// ---------------- Scan stage C: full exclusive scan, write offsets + cursor ----------------
__global__ __launch_bounds__(256) void scan_final(
    const int* __restrict__ counts, const int* __restrict__ blockPrefix,
    int* __restrict__ offsets, int* __restrict__ cursor)
{
    __shared__ int sums[256];
    int t = threadIdx.x;
    int idx = (blockIdx.x * 256 + t) * 4;
    int4 v = make_int4(0, 0, 0, 0);
    if (idx < N_NODES) v = *reinterpret_cast<const int4*>(counts + idx);
    int s = v.x + v.y + v.z + v.w;
    sums[t] = s;
    __syncthreads();
    for (int off = 1; off < 256; off <<= 1) {
        int u = (t >= off) ? sums[t - off] : 0;
        __syncthreads();
        sums[t] += u;
        __syncthreads();
    }
    int run = blockPrefix[blockIdx.x] + sums[t] - s;
    if (idx < N_NODES) {
        int4 o;
        o.x = run;
        o.y = run + v.x;
        o.z = run + v.x + v.y;
        o.w = run + v.x + v.y + v.z;
        *reinterpret_cast<int4*>(offsets + idx) = o;
        *reinterpret_cast<int4*>(cursor + idx)  = o;
    }
}

// ---------------- CSR build: scatter edge srcs into buckets ----------------
__global__ __launch_bounds__(256) void fill_kernel(
    const int* __restrict__ src, const int* __restrict__ dst,
    int* __restrict__ cursor, int* __restrict__ csr_src, int E)
{
    int e = blockIdx.x * blockDim.x + threadIdx.x;
    if (e < E) {
        int d = dst[e];
        int slot = atomicAdd(&cursor[d], 1);
        csr_src[slot] = src[e];
    }
}

// ---------------- Gather-reduce: one wave per node -> h in bf16 ----------------
// lane l accumulates columns 2l, 2l+1 in registers; packs to bf16x2 on store.
__global__ __launch_bounds__(256) void gather_kernel(
    const float* __restrict__ feat, const float* __restrict__ norm,
    const int* __restrict__ offsets, const int* __restrict__ counts,
    const int* __restrict__ csr_src, unsigned short* __restrict__ h)
{
    int wid  = (blockIdx.x * blockDim.x + threadIdx.x) >> 6;
    int lane = threadIdx.x & 63;
    if (wid >= N_NODES) return;

    const int deg = counts[wid];
    float a0, a1;
    if (deg == 0) {
        float2 v = *reinterpret_cast<const float2*>(feat + (size_t)wid * D + lane * 2);
        a0 = v.x; a1 = v.y;
    } else {
        const int base = offsets[wid];
        a0 = 0.f; a1 = 0.f;
        int i = 0;
        for (; i + 2 <= deg; i += 2) {
            int s0 = csr_src[base + i];
            int s1 = csr_src[base + i + 1];
            float n0 = norm[s0];
            float n1 = norm[s1];
            float2 v0 = *reinterpret_cast<const float2*>(feat + (size_t)s0 * D + lane * 2);
            float2 v1 = *reinterpret_cast<const float2*>(feat + (size_t)s1 * D + lane * 2);
            a0 += v0.x * n0 + v1.x * n1;
            a1 += v0.y * n0 + v1.y * n1;
        }
        if (i < deg) {
            int s0 = csr_src[base + i];
            float n0 = norm[s0];
            float2 v0 = *reinterpret_cast<const float2*>(feat + (size_t)s0 * D + lane * 2);
            a0 += v0.x * n0;
            a1 += v0.y * n0;
        }
        float nd = norm[wid];
        a0 *= nd; a1 *= nd;
    }
    unsigned int packed = (unsigned int)f2bf(a0) | ((unsigned int)f2bf(a1) << 16);
    *reinterpret_cast<unsigned int*>(h + (size_t)wid * D + lane * 2) = packed;
}

// ---------------- W f32 -> bf16 ----------------
__global__ __launch_bounds__(256) void wconvert(
    const float* __restrict__ W, unsigned short* __restrict__ Wb)
{
    int i = blockIdx.x * blockDim.x + threadIdx.x;   // 16384 threads
    Wb[i] = f2bf(W[i]);
}

// ---------------- Node apply via MFMA: out = relu(h @ W^T + b) ----------------
// One wave per 16-row tile (50000 = 3125 * 16). A = h[16x128], B = W^T.
// A frag: lane holds row (lane&15), k = (lane>>4)*8 + j  -> 16B contiguous.
// B frag: lane holds col n = n0*16 + (lane&15) = W row n, same k mapping.
// C/D (m89-verified): col = lane&15, row = (lane>>4)*4 + reg.
__global__ __launch_bounds__(256) void node_apply_mfma(
    const unsigned short* __restrict__ h,
    const unsigned short* __restrict__ Wb,
    const float* __restrict__ bias,
    float* __restrict__ out)
{
    int gw = (blockIdx.x * blockDim.x + threadIdx.x) >> 6;
    if (gw >= N_NODES / 16) return;
    const int lane = threadIdx.x & 63;
    const int mr = lane & 15;
    const int kg = lane >> 4;

    const size_t abase = (size_t)(gw * 16 + mr) * D + kg * 8;
    bf16x8 a0 = *reinterpret_cast<const bf16x8*>(h + abase);
    bf16x8 a1 = *reinterpret_cast<const bf16x8*>(h + abase + 32);
    bf16x8 a2 = *reinterpret_cast<const bf16x8*>(h + abase + 64);
    bf16x8 a3 = *reinterpret_cast<const bf16x8*>(h + abase + 96);

    const int orow0 = gw * 16 + kg * 4;
    #pragma unroll
    for (int n0 = 0; n0 < 8; ++n0) {
        const size_t bbase = (size_t)(n0 * 16 + mr) * D + kg * 8;
        bf16x8 b0 = *reinterpret_cast<const bf16x8*>(Wb + bbase);
        bf16x8 b1 = *reinterpret_cast<const bf16x8*>(Wb + bbase + 32);
        bf16x8 b2 = *reinterpret_cast<const bf16x8*>(Wb + bbase + 64);
        bf16x8 b3 = *reinterpret_cast<const bf16x8*>(Wb + bbase + 96);
        f32x4 acc = {0.f, 0.f, 0.f, 0.f};
        acc = __builtin_amdgcn_mfma_f32_16x16x32_bf16(a0, b0, acc, 0, 0, 0);
        acc = __builtin_amdgcn_mfma_f32_16x16x32_bf16(a1, b1, acc, 0, 0, 0);
        acc = __builtin_amdgcn_mfma_f32_16x16x32_bf16(a2, b2, acc, 0, 0, 0);
        acc = __builtin_amdgcn_mfma_f32_16x16x32_bf16(a3, b3, acc, 0, 0, 0);

        const int c = n0 * 16 + mr;
        const float bv = bias[c];
        #pragma unroll
        for (int j = 0; j < 4; ++j) {
            float r = acc[j] + bv;
            out[(size_t)(orow0 + j) * D + c] = r > 0.f ? r : 0.f;
        }
    }
}

extern "C" void kernel_launch(void* const* d_in, const int* in_sizes, int n_in,
                              void* d_out, int out_size, void* d_ws, size_t ws_size,
                              hipStream_t stream) {
    const float* feat = (const float*)d_in[0];
    const float* norm = (const float*)d_in[1];
    const float* W    = (const float*)d_in[2];
    const float* bias = (const float*)d_in[3];
    const int*   src  = (const int*)d_in[4];
    const int*   dst  = (const int*)d_in[5];
    float* out = (float*)d_out;

    char* ws = (char*)d_ws;
    unsigned short* h       = (unsigned short*)ws;                       // 12.8 MB
    int*            counts  = (int*)(ws + (size_t)N_NODES * D * sizeof(unsigned short));
    int*            offsets = counts + N_NODES;
    int*            cursor  = offsets + N_NODES;
    int*            csr_src = cursor + N_NODES;                          // 2.4 MB
    int*            blockSums = csr_src + N_EDGES;                       // 49 ints
    unsigned short* Wb      = (unsigned short*)(blockSums + 64);         // 32 KB

    hipMemsetAsync(counts, 0, (size_t)N_NODES * sizeof(int), stream);

    const int egrid = (N_EDGES + 255) / 256;
    hist_kernel<<<egrid, 256, 0, stream>>>(dst, counts, N_EDGES);
    scan_partial<<<SCAN_NB, 256, 0, stream>>>(counts, blockSums);
    scan_blocksums<<<1, 64, 0, stream>>>(blockSums);
    scan_final<<<SCAN_NB, 256, 0, stream>>>(counts, blockSums, offsets, cursor);
    fill_kernel<<<egrid, 256, 0, stream>>>(src, dst, cursor, csr_src, N_EDGES);
    wconvert<<<64, 256, 0, stream>>>(W, Wb);
    gather_kernel<<<(N_NODES + 3) / 4, 256, 0, stream>>>(feat, norm, offsets, counts, csr_src, h);
    node_apply_mfma<<<(N_NODES / 16 + 3) / 4, 256, 0, stream>>>(h, Wb, bias, out);
}

// Round 5
// 133.096 us; speedup vs baseline: 4.4536x; 1.1116x over previous
//
#include <hip/hip_runtime.h>

#define N_NODES 50000
#define N_EDGES 600000
#define D 128
#define SCAN_NB 49   // ceil(50000 / 1024)

typedef __attribute__((ext_vector_type(8))) short bf16x8;
typedef __attribute__((ext_vector_type(4))) float f32x4;

__device__ inline unsigned short f2bf(float f) {
    unsigned int u = __builtin_bit_cast(unsigned int, f);
    unsigned int r = (u + 0x7FFFu + ((u >> 16) & 1u)) >> 16;   // RNE
    return (unsigned short)r;
}
__device__ inline float bf_lo(unsigned int u) {
    return __builtin_bit_cast(float, u << 16);
}
__device__ inline float bf_hi(unsigned int u) {
    return __builtin_bit_cast(float, u & 0xFFFF0000u);
}

// ---------------- CSR build: histogram ----------------
__global__ __launch_bounds__(256) void hist_kernel(
    const int* __restrict__ dst, int* __restrict__ counts, int E)
{
    int e = blockIdx.x * blockDim.x + threadIdx.x;
    if (e < E) atomicAdd(&counts[dst[e]], 1);
}

// ---------------- Scan stage A: per-block sums ----------------
__global__ __launch_bounds__(256) void scan_partial(
    const int* __restrict__ counts, int* __restrict__ blockSums)
{
    __shared__ int red[256];
    int t = threadIdx.x;
    int idx = (blockIdx.x * 256 + t) * 4;
    int s = 0;
    if (idx < N_NODES) {
        int4 v = *reinterpret_cast<const int4*>(counts + idx);
        s = v.x + v.y + v.z + v.w;
    }
    red[t] = s;
    __syncthreads();
    for (int off = 128; off > 0; off >>= 1) {
        if (t < off) red[t] += red[t + off];
        __syncthreads();
    }
    if (t == 0) blockSums[blockIdx.x] = red[0];
}

// ---------------- Scan stage B: exclusive prefix over 49 block sums ----------------
__global__ __launch_bounds__(64) void scan_blocksums(int* __restrict__ blockSums)
{
    __shared__ int s[64];
    int t = threadIdx.x;
    s[t] = (t < SCAN_NB) ? blockSums[t] : 0;
    __syncthreads();
    if (t == 0) {
        int run = 0;
        for (int i = 0; i < SCAN_NB; ++i) { int v = s[i]; s[i] = run; run += v; }
    }
    __syncthreads();
    if (t < SCAN_NB) blockSums[t] = s[t];
}

// ---------------- Scan stage C: full exclusive scan ----------------
__global__ __launch_bounds__(256) void scan_final(
    const int* __restrict__ counts, const int* __restrict__ blockPrefix,
    int* __restrict__ offsets, int* __restrict__ cursor)
{
    __shared__ int sums[256];
    int t = threadIdx.x;
    int idx = (blockIdx.x * 256 + t) * 4;
    int4 v = make_int4(0, 0, 0, 0);
    if (idx < N_NODES) v = *reinterpret_cast<const int4*>(counts + idx);
    int s = v.x + v.y + v.z + v.w;
    sums[t] = s;
    __syncthreads();
    for (int off = 1; off < 256; off <<= 1) {
        int u = (t >= off) ? sums[t - off] : 0;
        __syncthreads();
        sums[t] += u;
        __syncthreads();
    }
    int run = blockPrefix[blockIdx.x] + sums[t] - s;
    if (idx < N_NODES) {
        int4 o;
        o.x = run;
        o.y = run + v.x;
        o.z = run + v.x + v.y;
        o.w = run + v.x + v.y + v.z;
        *reinterpret_cast<int4*>(offsets + idx) = o;
        *reinterpret_cast<int4*>(cursor + idx)  = o;
    }
}

// ---------------- CSR build: scatter edge srcs into buckets ----------------
__global__ __launch_bounds__(256) void fill_kernel(
    const int* __restrict__ src, const int* __restrict__ dst,
    int* __restrict__ cursor, int* __restrict__ csr_src, int E)
{
    int e = blockIdx.x * blockDim.x + threadIdx.x;
    if (e < E) {
        int d = dst[e];
        int slot = atomicAdd(&cursor[d], 1);
        csr_src[slot] = src[e];
    }
}

// ---------------- premul: g = bf16(feat * norm_src), the per-edge message source ----------------
// thread t: row = gid/32, cols (gid%32)*4 .. +3
__global__ __launch_bounds__(256) void premul_kernel(
    const float* __restrict__ feat, const float* __restrict__ norm,
    unsigned short* __restrict__ g)
{
    int gid = blockIdx.x * blockDim.x + threadIdx.x;   // 50000*32 total
    int row = gid >> 5;
    int c4  = (gid & 31) * 4;
    float nr = norm[row];
    float4 v = *reinterpret_cast<const float4*>(feat + (size_t)row * D + c4);
    ushort4 o;
    o.x = f2bf(v.x * nr);
    o.y = f2bf(v.y * nr);
    o.z = f2bf(v.z * nr);
    o.w = f2bf(v.w * nr);
    *reinterpret_cast<ushort4*>(g + (size_t)row * D + c4) = o;
}

// ---------------- W f32 -> bf16 ----------------
__global__ __launch_bounds__(256) void wconvert(
    const float* __restrict__ W, unsigned short* __restrict__ Wb)
{
    int i = blockIdx.x * blockDim.x + threadIdx.x;   // 16384 threads
    Wb[i] = f2bf(W[i]);
}

// ---------------- Fused gather + MFMA node-apply ----------------
// Block = 4 waves = 16 nodes (50000 = 3125*16).
// Phase 1: wave w gathers nodes w*4..w*4+3 -> LDS rows (stride 136 bf16, 2-way banks).
// Phase 2: wave w computes output col-blocks n0 = 2w, 2w+1 via 16x16x32 bf16 MFMA.
// A frag: lane(mr,kg) holds row mr, k = kg*8 + 32*s + j. C/D: col=lane&15, row=kg*4+reg (m89).
__global__ __launch_bounds__(256) void gather_mfma(
    const unsigned short* __restrict__ g,
    const float* __restrict__ feat, const float* __restrict__ norm,
    const int* __restrict__ offsets, const int* __restrict__ counts,
    const int* __restrict__ csr_src,
    const unsigned short* __restrict__ Wb,
    const float* __restrict__ bias,
    float* __restrict__ out)
{
    __shared__ __align__(16) unsigned short hsh[16 * 136];
    const int t    = threadIdx.x;
    const int w    = t >> 6;
    const int lane = t & 63;
    const int nbase = blockIdx.x * 16;

    // ---- Phase 1: gather 4 nodes per wave; lane handles cols 2l, 2l+1 ----
    #pragma unroll
    for (int q = 0; q < 4; ++q) {
        const int ln   = w * 4 + q;
        const int node = nbase + ln;
        const int deg  = counts[node];
        float a0, a1;
        if (deg == 0) {
            float2 v = *reinterpret_cast<const float2*>(feat + (size_t)node * D + lane * 2);
            a0 = v.x; a1 = v.y;
        } else {
            const int base = offsets[node];
            a0 = 0.f; a1 = 0.f;
            int i = 0;
            for (; i + 4 <= deg; i += 4) {
                int s0 = csr_src[base + i];
                int s1 = csr_src[base + i + 1];
                int s2 = csr_src[base + i + 2];
                int s3 = csr_src[base + i + 3];
                unsigned int u0 = *reinterpret_cast<const unsigned int*>(g + (size_t)s0 * D + lane * 2);
                unsigned int u1 = *reinterpret_cast<const unsigned int*>(g + (size_t)s1 * D + lane * 2);
                unsigned int u2 = *reinterpret_cast<const unsigned int*>(g + (size_t)s2 * D + lane * 2);
                unsigned int u3 = *reinterpret_cast<const unsigned int*>(g + (size_t)s3 * D + lane * 2);
                a0 += bf_lo(u0) + bf_lo(u1) + bf_lo(u2) + bf_lo(u3);
                a1 += bf_hi(u0) + bf_hi(u1) + bf_hi(u2) + bf_hi(u3);
            }
            for (; i < deg; ++i) {
                int s0 = csr_src[base + i];
                unsigned int u0 = *reinterpret_cast<const unsigned int*>(g + (size_t)s0 * D + lane * 2);
                a0 += bf_lo(u0);
                a1 += bf_hi(u0);
            }
            float nd = norm[node];
            a0 *= nd; a1 *= nd;
        }
        unsigned int packed = (unsigned int)f2bf(a0) | ((unsigned int)f2bf(a1) << 16);
        *reinterpret_cast<unsigned int*>(&hsh[ln * 136 + lane * 2]) = packed;
    }
    __syncthreads();

    // ---- Phase 2: MFMA. wave w -> col blocks n0 = 2w, 2w+1 ----
    const int mr = lane & 15;
    const int kg = lane >> 4;

    bf16x8 a0 = *reinterpret_cast<const bf16x8*>(&hsh[mr * 136 + kg * 8]);
    bf16x8 a1 = *reinterpret_cast<const bf16x8*>(&hsh[mr * 136 + kg * 8 + 32]);
    bf16x8 a2 = *reinterpret_cast<const bf16x8*>(&hsh[mr * 136 + kg * 8 + 64]);
    bf16x8 a3 = *reinterpret_cast<const bf16x8*>(&hsh[mr * 136 + kg * 8 + 96]);

    const int orow0 = nbase + kg * 4;
    #pragma unroll
    for (int nn = 0; nn < 2; ++nn) {
        const int n0 = w * 2 + nn;
        const size_t bbase = (size_t)(n0 * 16 + mr) * D + kg * 8;
        bf16x8 b0 = *reinterpret_cast<const bf16x8*>(Wb + bbase);
        bf16x8 b1 = *reinterpret_cast<const bf16x8*>(Wb + bbase + 32);
        bf16x8 b2 = *reinterpret_cast<const bf16x8*>(Wb + bbase + 64);
        bf16x8 b3 = *reinterpret_cast<const bf16x8*>(Wb + bbase + 96);
        f32x4 acc = {0.f, 0.f, 0.f, 0.f};
        acc = __builtin_amdgcn_mfma_f32_16x16x32_bf16(a0, b0, acc, 0, 0, 0);
        acc = __builtin_amdgcn_mfma_f32_16x16x32_bf16(a1, b1, acc, 0, 0, 0);
        acc = __builtin_amdgcn_mfma_f32_16x16x32_bf16(a2, b2, acc, 0, 0, 0);
        acc = __builtin_amdgcn_mfma_f32_16x16x32_bf16(a3, b3, acc, 0, 0, 0);

        const int c = n0 * 16 + mr;
        const float bv = bias[c];
        #pragma unroll
        for (int j = 0; j < 4; ++j) {
            float r = acc[j] + bv;
            out[(size_t)(orow0 + j) * D + c] = r > 0.f ? r : 0.f;
        }
    }
}

extern "C" void kernel_launch(void* const* d_in, const int* in_sizes, int n_in,
                              void* d_out, int out_size, void* d_ws, size_t ws_size,
                              hipStream_t stream) {
    const float* feat = (const float*)d_in[0];
    const float* norm = (const float*)d_in[1];
    const float* W    = (const float*)d_in[2];
    const float* bias = (const float*)d_in[3];
    const int*   src  = (const int*)d_in[4];
    const int*   dst  = (const int*)d_in[5];
    float* out = (float*)d_out;

    char* ws = (char*)d_ws;
    unsigned short* g        = (unsigned short*)ws;                        // 12.8 MB
    int*            counts   = (int*)(ws + (size_t)N_NODES * D * sizeof(unsigned short));
    int*            offsets  = counts + N_NODES;
    int*            cursor   = offsets + N_NODES;
    int*            csr_src  = cursor + N_NODES;                           // 2.4 MB
    int*            blockSums = csr_src + N_EDGES;                         // 64 ints
    unsigned short* Wb       = (unsigned short*)(blockSums + 64);          // 32 KB (16B-aligned)

    hipMemsetAsync(counts, 0, (size_t)N_NODES * sizeof(int), stream);

    const int egrid = (N_EDGES + 255) / 256;
    hist_kernel<<<egrid, 256, 0, stream>>>(dst, counts, N_EDGES);
    scan_partial<<<SCAN_NB, 256, 0, stream>>>(counts, blockSums);
    scan_blocksums<<<1, 64, 0, stream>>>(blockSums);
    scan_final<<<SCAN_NB, 256, 0, stream>>>(counts, blockSums, offsets, cursor);
    fill_kernel<<<egrid, 256, 0, stream>>>(src, dst, cursor, csr_src, N_EDGES);
    premul_kernel<<<N_NODES * 32 / 256, 256, 0, stream>>>(feat, norm, g);
    wconvert<<<64, 256, 0, stream>>>(W, Wb);
    gather_mfma<<<N_NODES / 16, 256, 0, stream>>>(g, feat, norm, offsets, counts, csr_src, Wb, bias, out);
}

// Round 6
// 111.665 us; speedup vs baseline: 5.3083x; 1.1919x over previous
//
#include <hip/hip_runtime.h>

#define N_NODES 50000
#define N_EDGES 600000
#define D 128
#define SCAN_NB 49   // ceil(50000 / 1024)

typedef __attribute__((ext_vector_type(8))) short bf16x8;
typedef __attribute__((ext_vector_type(4))) float f32x4;

__device__ inline unsigned int f2bf_u(float f) {
    unsigned int u = __builtin_bit_cast(unsigned int, f);
    return (u + 0x7FFFu + ((u >> 16) & 1u)) >> 16;   // RNE
}
__device__ inline unsigned int pack2(float lo, float hi) {
    return f2bf_u(lo) | (f2bf_u(hi) << 16);
}
__device__ inline float bf_lo(unsigned int u) {
    return __builtin_bit_cast(float, u << 16);
}
__device__ inline float bf_hi(unsigned int u) {
    return __builtin_bit_cast(float, u & 0xFFFF0000u);
}

// ---------------- Fused init: premul g = bf16(feat*norm) | Wb = bf16(W) | counts = 0 ----------------
__global__ __launch_bounds__(256) void init_kernel(
    const float* __restrict__ feat, const float* __restrict__ norm,
    const float* __restrict__ W,
    unsigned short* __restrict__ g, unsigned short* __restrict__ Wb,
    int* __restrict__ counts)
{
    const int b = blockIdx.x, t = threadIdx.x;
    if (b < 3125) {
        // premul: 800000 threads, 8 floats each
        int gid = b * 256 + t;
        int row = gid >> 4;
        int c8  = (gid & 15) * 8;
        float nr = norm[row];
        float4 f0 = *reinterpret_cast<const float4*>(feat + (size_t)row * D + c8);
        float4 f1 = *reinterpret_cast<const float4*>(feat + (size_t)row * D + c8 + 4);
        uint4 o;
        o.x = pack2(f0.x * nr, f0.y * nr);
        o.y = pack2(f0.z * nr, f0.w * nr);
        o.z = pack2(f1.x * nr, f1.y * nr);
        o.w = pack2(f1.z * nr, f1.w * nr);
        *reinterpret_cast<uint4*>(g + (size_t)row * D + c8) = o;
    } else if (b < 3141) {
        // wconvert: 4096 threads, 4 floats each
        int j = (b - 3125) * 256 + t;
        float4 w = *reinterpret_cast<const float4*>(W + (size_t)j * 4);
        ushort4 o;
        o.x = (unsigned short)f2bf_u(w.x);
        o.y = (unsigned short)f2bf_u(w.y);
        o.z = (unsigned short)f2bf_u(w.z);
        o.w = (unsigned short)f2bf_u(w.w);
        *reinterpret_cast<ushort4*>(Wb + (size_t)j * 4) = o;
    } else {
        // zero counts: 12500 int4s
        int idx = (b - 3141) * 256 + t;
        if (idx < 12500) *reinterpret_cast<int4*>(counts + idx * 4) = make_int4(0, 0, 0, 0);
    }
}

// ---------------- CSR build: histogram ----------------
__global__ __launch_bounds__(256) void hist_kernel(
    const int* __restrict__ dst, int* __restrict__ counts, int E)
{
    int e = blockIdx.x * blockDim.x + threadIdx.x;
    if (e < E) atomicAdd(&counts[dst[e]], 1);
}

// ---------------- Scan stage A: per-block sums (1024 counts/block) ----------------
__global__ __launch_bounds__(256) void scan_partial(
    const int* __restrict__ counts, int* __restrict__ blockSums)
{
    __shared__ int red[256];
    int t = threadIdx.x;
    int idx = (blockIdx.x * 256 + t) * 4;
    int s = 0;
    if (idx < N_NODES) {
        int4 v = *reinterpret_cast<const int4*>(counts + idx);
        s = v.x + v.y + v.z + v.w;
    }
    red[t] = s;
    __syncthreads();
    for (int off = 128; off > 0; off >>= 1) {
        if (t < off) red[t] += red[t + off];
        __syncthreads();
    }
    if (t == 0) blockSums[blockIdx.x] = red[0];
}

// ---------------- Scan stage B: full exclusive scan (block prefix inlined) ----------------
__global__ __launch_bounds__(256) void scan_final(
    const int* __restrict__ counts, const int* __restrict__ blockSums,
    int* __restrict__ offsets, int* __restrict__ cursor)
{
    __shared__ int sums[256];
    __shared__ int bs[64];
    __shared__ int bpref;
    int t = threadIdx.x;
    if (t < SCAN_NB) bs[t] = blockSums[t];
    int idx = (blockIdx.x * 256 + t) * 4;
    int4 v = make_int4(0, 0, 0, 0);
    if (idx < N_NODES) v = *reinterpret_cast<const int4*>(counts + idx);
    int s = v.x + v.y + v.z + v.w;
    sums[t] = s;
    __syncthreads();
    if (t == 0) {
        int run = 0;
        for (int j = 0; j < blockIdx.x; ++j) run += bs[j];
        bpref = run;
    }
    for (int off = 1; off < 256; off <<= 1) {
        int u = (t >= off) ? sums[t - off] : 0;
        __syncthreads();
        sums[t] += u;
        __syncthreads();
    }
    int run = bpref + sums[t] - s;
    if (idx < N_NODES) {
        int4 o;
        o.x = run;
        o.y = run + v.x;
        o.z = run + v.x + v.y;
        o.w = run + v.x + v.y + v.z;
        *reinterpret_cast<int4*>(offsets + idx) = o;
        *reinterpret_cast<int4*>(cursor + idx)  = o;
    }
}

// ---------------- CSR build: scatter edge srcs into buckets ----------------
__global__ __launch_bounds__(256) void fill_kernel(
    const int* __restrict__ src, const int* __restrict__ dst,
    int* __restrict__ cursor, int* __restrict__ csr_src, int E)
{
    int e = blockIdx.x * blockDim.x + threadIdx.x;
    if (e < E) {
        int d = dst[e];
        int slot = atomicAdd(&cursor[d], 1);
        csr_src[slot] = src[e];
    }
}

// ---------------- Fused gather + MFMA node-apply ----------------
// Block = 4 waves = 16 nodes. Phase 1 (node-parallel): lane group kg = lane>>4 owns
// node ln = w*4+kg; lane mr = lane&15 owns columns mr*8..mr*8+7 (16B of the row).
// One wave-instruction gathers 4 rows (1KB). Unroll-4 -> 16 rows in flight.
// Phase 2: wave w computes output col-blocks n0 = 2w, 2w+1 via 16x16x32 bf16 MFMA
// (fragment mapping empirically verified rounds 3-5).
__global__ __launch_bounds__(256) void gather_mfma(
    const unsigned short* __restrict__ g,
    const float* __restrict__ feat, const float* __restrict__ norm,
    const int* __restrict__ offsets, const int* __restrict__ counts,
    const int* __restrict__ csr_src,
    const unsigned short* __restrict__ Wb,
    const float* __restrict__ bias,
    float* __restrict__ out)
{
    __shared__ __align__(16) unsigned short hsh[16 * 136];
    const int t    = threadIdx.x;
    const int w    = t >> 6;
    const int lane = t & 63;
    const int kg   = lane >> 4;
    const int mr   = lane & 15;
    const int nbase = blockIdx.x * 16;

    // ---- Phase 1: gather (node-parallel across kg groups) ----
    const int ln   = w * 4 + kg;
    const int node = nbase + ln;
    const int deg  = counts[node];
    const int base = offsets[node];

    float a0 = 0.f, a1 = 0.f, a2 = 0.f, a3 = 0.f;
    float a4 = 0.f, a5 = 0.f, a6 = 0.f, a7 = 0.f;
    const unsigned short* gcol = g + mr * 8;

    int i = 0;
    for (; i + 4 <= deg; i += 4) {
        int s0 = csr_src[base + i];
        int s1 = csr_src[base + i + 1];
        int s2 = csr_src[base + i + 2];
        int s3 = csr_src[base + i + 3];
        uint4 v0 = *reinterpret_cast<const uint4*>(gcol + (size_t)s0 * D);
        uint4 v1 = *reinterpret_cast<const uint4*>(gcol + (size_t)s1 * D);
        uint4 v2 = *reinterpret_cast<const uint4*>(gcol + (size_t)s2 * D);
        uint4 v3 = *reinterpret_cast<const uint4*>(gcol + (size_t)s3 * D);
        a0 += bf_lo(v0.x) + bf_lo(v1.x) + bf_lo(v2.x) + bf_lo(v3.x);
        a1 += bf_hi(v0.x) + bf_hi(v1.x) + bf_hi(v2.x) + bf_hi(v3.x);
        a2 += bf_lo(v0.y) + bf_lo(v1.y) + bf_lo(v2.y) + bf_lo(v3.y);
        a3 += bf_hi(v0.y) + bf_hi(v1.y) + bf_hi(v2.y) + bf_hi(v3.y);
        a4 += bf_lo(v0.z) + bf_lo(v1.z) + bf_lo(v2.z) + bf_lo(v3.z);
        a5 += bf_hi(v0.z) + bf_hi(v1.z) + bf_hi(v2.z) + bf_hi(v3.z);
        a6 += bf_lo(v0.w) + bf_lo(v1.w) + bf_lo(v2.w) + bf_lo(v3.w);
        a7 += bf_hi(v0.w) + bf_hi(v1.w) + bf_hi(v2.w) + bf_hi(v3.w);
    }
    for (; i < deg; ++i) {
        int s0 = csr_src[base + i];
        uint4 v0 = *reinterpret_cast<const uint4*>(gcol + (size_t)s0 * D);
        a0 += bf_lo(v0.x); a1 += bf_hi(v0.x);
        a2 += bf_lo(v0.y); a3 += bf_hi(v0.y);
        a4 += bf_lo(v0.z); a5 += bf_hi(v0.z);
        a6 += bf_lo(v0.w); a7 += bf_hi(v0.w);
    }

    if (deg == 0) {
        float4 f0 = *reinterpret_cast<const float4*>(feat + (size_t)node * D + mr * 8);
        float4 f1 = *reinterpret_cast<const float4*>(feat + (size_t)node * D + mr * 8 + 4);
        a0 = f0.x; a1 = f0.y; a2 = f0.z; a3 = f0.w;
        a4 = f1.x; a5 = f1.y; a6 = f1.z; a7 = f1.w;
    } else {
        float nd = norm[node];
        a0 *= nd; a1 *= nd; a2 *= nd; a3 *= nd;
        a4 *= nd; a5 *= nd; a6 *= nd; a7 *= nd;
    }
    uint4 o;
    o.x = pack2(a0, a1);
    o.y = pack2(a2, a3);
    o.z = pack2(a4, a5);
    o.w = pack2(a6, a7);
    *reinterpret_cast<uint4*>(&hsh[ln * 136 + mr * 8]) = o;
    __syncthreads();

    // ---- Phase 2: MFMA. wave w -> col blocks n0 = 2w, 2w+1 ----
    bf16x8 fa0 = *reinterpret_cast<const bf16x8*>(&hsh[mr * 136 + kg * 8]);
    bf16x8 fa1 = *reinterpret_cast<const bf16x8*>(&hsh[mr * 136 + kg * 8 + 32]);
    bf16x8 fa2 = *reinterpret_cast<const bf16x8*>(&hsh[mr * 136 + kg * 8 + 64]);
    bf16x8 fa3 = *reinterpret_cast<const bf16x8*>(&hsh[mr * 136 + kg * 8 + 96]);

    const int orow0 = nbase + kg * 4;
    #pragma unroll
    for (int nn = 0; nn < 2; ++nn) {
        const int n0 = w * 2 + nn;
        const size_t bbase = (size_t)(n0 * 16 + mr) * D + kg * 8;
        bf16x8 b0 = *reinterpret_cast<const bf16x8*>(Wb + bbase);
        bf16x8 b1 = *reinterpret_cast<const bf16x8*>(Wb + bbase + 32);
        bf16x8 b2 = *reinterpret_cast<const bf16x8*>(Wb + bbase + 64);
        bf16x8 b3 = *reinterpret_cast<const bf16x8*>(Wb + bbase + 96);
        f32x4 acc = {0.f, 0.f, 0.f, 0.f};
        acc = __builtin_amdgcn_mfma_f32_16x16x32_bf16(fa0, b0, acc, 0, 0, 0);
        acc = __builtin_amdgcn_mfma_f32_16x16x32_bf16(fa1, b1, acc, 0, 0, 0);
        acc = __builtin_amdgcn_mfma_f32_16x16x32_bf16(fa2, b2, acc, 0, 0, 0);
        acc = __builtin_amdgcn_mfma_f32_16x16x32_bf16(fa3, b3, acc, 0, 0, 0);

        const int c = n0 * 16 + mr;
        const float bv = bias[c];
        #pragma unroll
        for (int j = 0; j < 4; ++j) {
            float r = acc[j] + bv;
            out[(size_t)(orow0 + j) * D + c] = r > 0.f ? r : 0.f;
        }
    }
}

extern "C" void kernel_launch(void* const* d_in, const int* in_sizes, int n_in,
                              void* d_out, int out_size, void* d_ws, size_t ws_size,
                              hipStream_t stream) {
    const float* feat = (const float*)d_in[0];
    const float* norm = (const float*)d_in[1];
    const float* W    = (const float*)d_in[2];
    const float* bias = (const float*)d_in[3];
    const int*   src  = (const int*)d_in[4];
    const int*   dst  = (const int*)d_in[5];
    float* out = (float*)d_out;

    char* ws = (char*)d_ws;
    unsigned short* g        = (unsigned short*)ws;                        // 12.8 MB
    int*            counts   = (int*)(ws + (size_t)N_NODES * D * sizeof(unsigned short));
    int*            offsets  = counts + N_NODES;
    int*            cursor   = offsets + N_NODES;
    int*            csr_src  = cursor + N_NODES;                           // 2.4 MB
    int*            blockSums = csr_src + N_EDGES;                         // 64 ints
    unsigned short* Wb       = (unsigned short*)(blockSums + 64);          // 32 KB (16B-aligned)

    const int egrid = (N_EDGES + 255) / 256;
    init_kernel<<<3190, 256, 0, stream>>>(feat, norm, W, g, Wb, counts);
    hist_kernel<<<egrid, 256, 0, stream>>>(dst, counts, N_EDGES);
    scan_partial<<<SCAN_NB, 256, 0, stream>>>(counts, blockSums);
    scan_final<<<SCAN_NB, 256, 0, stream>>>(counts, blockSums, offsets, cursor);
    fill_kernel<<<egrid, 256, 0, stream>>>(src, dst, cursor, csr_src, N_EDGES);
    gather_mfma<<<N_NODES / 16, 256, 0, stream>>>(g, feat, norm, offsets, counts, csr_src, Wb, bias, out);
}